// Round 12
// baseline (683.541 us; speedup 1.0000x reference)
//
#include <hip/hip_runtime.h>
#include <hip/hip_bf16.h>

#define LN_EPS 1e-5f
#define EPB 4096          // edges per block in bucket passes
typedef unsigned short u16;
typedef unsigned short us8 __attribute__((ext_vector_type(8)));
typedef short s8v __attribute__((ext_vector_type(8)));   // 8 bf16 (4 VGPRs) MFMA frag
typedef float f32x4 __attribute__((ext_vector_type(4))); // MFMA acc

static __device__ __forceinline__ float bf2f(u16 x) {
    return __uint_as_float(((unsigned int)x) << 16);
}
static __device__ __forceinline__ u16 f2bf(float f) {
    unsigned int u = __float_as_uint(f);
    return (u16)((u + 0x7fff + ((u >> 16) & 1)) >> 16);  // RNE
}

// ================= CSR build: two-level counting sort (bucket = dst>>8) =================
__global__ __launch_bounds__(256) void k_p1_hist(const int* __restrict__ dst,
                                                 int* __restrict__ blockhist,
                                                 int* __restrict__ dhist,
                                                 int E, int NB) {
    extern __shared__ int h[];
    int b = blockIdx.x, t = threadIdx.x;
    if (b == 0) dhist[t] = 0;          // zero degree histogram for later
    for (int j = t; j < NB; j += 256) h[j] = 0;
    __syncthreads();
    int e0 = b * EPB, e1 = min(E, e0 + EPB);
    for (int e = e0 + t; e < e1; e += 256)
        atomicAdd(&h[dst[e] >> 8], 1);
    __syncthreads();
    for (int j = t; j < NB; j += 256)
        blockhist[(size_t)b * NB + j] = h[j];
}

__global__ __launch_bounds__(512) void k_p2a(int* __restrict__ blockhist,
                                             int* __restrict__ btot, int NB, int NB1) {
    __shared__ int sd[512];
    int k = blockIdx.x, t = threadIdx.x;
    int v = (t < NB1) ? blockhist[(size_t)t * NB + k] : 0;
    sd[t] = v;
    __syncthreads();
    for (int off = 1; off < 512; off <<= 1) {
        int x = (t >= off) ? sd[t - off] : 0;
        __syncthreads();
        sd[t] += x;
        __syncthreads();
    }
    if (t < NB1) blockhist[(size_t)t * NB + k] = sd[t] - v;
    if (t == 511) btot[k] = sd[511];
}

// block 0: exclusive-scan bucket totals -> bbase; blocks >=1: bf16-transpose weights
__global__ __launch_bounds__(512) void k_p2b_prep(const int* __restrict__ btot,
                                                  int* __restrict__ bbase,
                                                  int* __restrict__ row_ptr,
                                                  int NB, int N, int E,
                                                  const float* __restrict__ W1,
                                                  const float* __restrict__ W2,
                                                  const float* __restrict__ Wm1,
                                                  u16* __restrict__ Wtb) {
    if (blockIdx.x == 0) {
        __shared__ int sd[512];
        int t = threadIdx.x;
        int v = (t < NB) ? btot[t] : 0;
        sd[t] = v;
        __syncthreads();
        for (int off = 1; off < 512; off <<= 1) {
            int x = (t >= off) ? sd[t - off] : 0;
            __syncthreads();
            sd[t] += x;
            __syncthreads();
        }
        if (t < NB) bbase[t] = sd[t] - v;
        if (t == 0) { bbase[NB] = E; row_ptr[N] = E; }
    } else {
        int idx = (blockIdx.x - 1) * 512 + threadIdx.x;   // 3*4096 total
        if (idx < 3 * 4096) {
            int m = idx >> 12;
            int kc = idx & 4095;
            int col = kc >> 6, k = kc & 63;
            const float* W = (m == 0) ? W1 : (m == 1) ? W2 : Wm1;
            Wtb[idx] = f2bf(W[k * 64 + col]);
        }
    }
}

__global__ __launch_bounds__(256) void k_p3_scatter(const int* __restrict__ src,
                                                    const int* __restrict__ dst,
                                                    const int* __restrict__ blockhist,
                                                    const int* __restrict__ bbase,
                                                    int* __restrict__ entries,
                                                    int E, int NB) {
    extern __shared__ int cur[];
    int b = blockIdx.x, t = threadIdx.x;
    for (int j = t; j < NB; j += 256)
        cur[j] = bbase[j] + blockhist[(size_t)b * NB + j];
    __syncthreads();
    int e0 = b * EPB, e1 = min(E, e0 + EPB);
    for (int e = e0 + t; e < e1; e += 256) {
        int d = dst[e];
        int p = atomicAdd(&cur[d >> 8], 1);
        entries[p] = (src[e] << 8) | (d & 255);
    }
}

// p4: per-bucket counting sort by key (dst_local, src>>14) -> partition-ordered CSR
// also: deg[node], degree histogram (for degree-sorted gather permutation)
__global__ __launch_bounds__(256) void k_p4_csr(const int* __restrict__ entries,
                                                const int* __restrict__ bbase,
                                                int* __restrict__ row_ptr,
                                                float* __restrict__ dinv,
                                                int* __restrict__ csr_src,
                                                int* __restrict__ deg,
                                                int* __restrict__ dhist, int N) {
    __shared__ int bins[2048];
    __shared__ int sd[256];
    int k = blockIdx.x, t = threadIdx.x;
    int b0 = bbase[k], b1 = bbase[k + 1];
    #pragma unroll
    for (int j = 0; j < 8; ++j) bins[t * 8 + j] = 0;
    __syncthreads();
    for (int e = b0 + t; e < b1; e += 256) {
        int en = entries[e];
        int key = ((en & 255) << 3) | ((en >> 22) & 7);   // dst_local*8 + src_partition
        atomicAdd(&bins[key], 1);
    }
    __syncthreads();
    int c[8];
    int run = 0;
    #pragma unroll
    for (int j = 0; j < 8; ++j) {
        c[j] = run;
        run += bins[t * 8 + j];
    }
    sd[t] = run;
    __syncthreads();
    for (int off = 1; off < 256; off <<= 1) {
        int x = (t >= off) ? sd[t - off] : 0;
        __syncthreads();
        sd[t] += x;
        __syncthreads();
    }
    int excl = sd[t] - run;
    int node = (k << 8) + t;
    if (node < N) {
        row_ptr[node] = b0 + excl;
        dinv[node] = rsqrtf(1.0f + (float)run);
        deg[node] = run;
        atomicAdd(&dhist[min(run, 255)], 1);
    }
    #pragma unroll
    for (int j = 0; j < 8; ++j) bins[t * 8 + j] = excl + c[j];
    __syncthreads();
    for (int e = b0 + t; e < b1; e += 256) {
        int en = entries[e];
        int key = ((en & 255) << 3) | ((en >> 22) & 7);
        int p = atomicAdd(&bins[key], 1);
        csr_src[b0 + p] = en >> 8;
    }
}

// exclusive scan of 256 degree bins (in place: dhist -> cursor bases)
__global__ __launch_bounds__(256) void k_dscan(int* __restrict__ dhist) {
    __shared__ int sd[256];
    int t = threadIdx.x;
    int v = dhist[t];
    sd[t] = v;
    __syncthreads();
    for (int off = 1; off < 256; off <<= 1) {
        int x = (t >= off) ? sd[t - off] : 0;
        __syncthreads();
        sd[t] += x;
        __syncthreads();
    }
    dhist[t] = sd[t] - v;
}

// scatter node ids in degree order: nodeperm[rank] = node
__global__ __launch_bounds__(256) void k_dperm(const int* __restrict__ deg,
                                               int* __restrict__ dbase,
                                               int* __restrict__ nodeperm, int N) {
    int n = blockIdx.x * 256 + threadIdx.x;
    if (n < N) {
        int b = min(deg[n], 255);
        int p = atomicAdd(&dbase[b], 1);
        nodeperm[p] = n;
    }
}

// ===== LN prologue (row-major AG): lane covers cols {hi*8..+7} u {32+hi*8..+7} of row nr;
//       stats across the 4 hi-lanes via shfl_xor(16,32); emits MFMA A-frags =====
static __device__ __forceinline__ void ln_frags(const u16* __restrict__ AG,
                                                int nr, int hi,
                                                const float* __restrict__ dinv,
                                                const float* __restrict__ bias,
                                                const float* __restrict__ g,
                                                const float* __restrict__ beta,
                                                s8v a[2]) {
    float dd = dinv[nr];
    int f0 = hi * 8;
    us8 lo = *reinterpret_cast<const us8*>(AG + (size_t)nr * 64 + f0);
    us8 hv = *reinterpret_cast<const us8*>(AG + (size_t)nr * 64 + 32 + f0);
    float v[16];
    #pragma unroll
    for (int j = 0; j < 8; ++j) {
        v[j] = fmaxf(bf2f(lo[j]) * dd + bias[f0 + j], 0.f);
        v[8 + j] = fmaxf(bf2f(hv[j]) * dd + bias[32 + f0 + j], 0.f);
    }
    float s = 0.f;
    #pragma unroll
    for (int j = 0; j < 16; ++j) s += v[j];
    s += __shfl_xor(s, 16); s += __shfl_xor(s, 32);
    float mu = s * (1.0f / 64.0f);
    float vs = 0.f;
    #pragma unroll
    for (int j = 0; j < 16; ++j) {
        float d = v[j] - mu;
        vs += d * d;
    }
    vs += __shfl_xor(vs, 16); vs += __shfl_xor(vs, 32);
    float r = rsqrtf(vs * (1.0f / 64.0f) + LN_EPS);
    #pragma unroll
    for (int j = 0; j < 8; ++j) {
        a[0][j] = (short)f2bf((v[j] - mu) * r * g[f0 + j] + beta[f0 + j]);
        a[1][j] = (short)f2bf((v[8 + j] - mu) * r * g[32 + f0 + j] + beta[32 + f0 + j]);
    }
}

// ===== GEMM1: Hb[n][64] = (z[n][:] @ W1) * dinv[n]  (fp32 A, bf16 out, row-major) =====
__global__ __launch_bounds__(256) void k_gemm1(const float* __restrict__ A,
                                               const u16* __restrict__ Wtb,
                                               const float* __restrict__ dinv,
                                               u16* __restrict__ C, int N) {
    int tid = threadIdx.x;
    int wid = tid >> 6, l = tid & 63;
    int li = l & 15, hi = l >> 4;
    int n0 = blockIdx.x * 64 + wid * 16;
    if (n0 >= N) return;
    int k0 = hi * 8;

    s8v a[2];
    int nr = min(n0 + li, N - 1);
    #pragma unroll
    for (int kk = 0; kk < 2; ++kk) {
        const float* p = A + (size_t)nr * 64 + kk * 32 + k0;
        float4 f0 = *reinterpret_cast<const float4*>(p);
        float4 f1 = *reinterpret_cast<const float4*>(p + 4);
        a[kk][0] = (short)f2bf(f0.x); a[kk][1] = (short)f2bf(f0.y);
        a[kk][2] = (short)f2bf(f0.z); a[kk][3] = (short)f2bf(f0.w);
        a[kk][4] = (short)f2bf(f1.x); a[kk][5] = (short)f2bf(f1.y);
        a[kk][6] = (short)f2bf(f1.z); a[kk][7] = (short)f2bf(f1.w);
    }

    s8v b[4][2];
    #pragma unroll
    for (int ct = 0; ct < 4; ++ct)
        #pragma unroll
        for (int kk = 0; kk < 2; ++kk)
            b[ct][kk] = *reinterpret_cast<const s8v*>(Wtb + (ct * 16 + li) * 64 + kk * 32 + k0);

    f32x4 acc[4] = {{0.f, 0.f, 0.f, 0.f}, {0.f, 0.f, 0.f, 0.f},
                    {0.f, 0.f, 0.f, 0.f}, {0.f, 0.f, 0.f, 0.f}};
    #pragma unroll
    for (int kk = 0; kk < 2; ++kk)
        #pragma unroll
        for (int ct = 0; ct < 4; ++ct)
            acc[ct] = __builtin_amdgcn_mfma_f32_16x16x32_bf16(a[kk], b[ct][kk], acc[ct], 0, 0, 0);

    #pragma unroll
    for (int r = 0; r < 4; ++r) {
        int node = n0 + hi * 4 + r;
        if (node < N) {
            float dv = dinv[node];
            #pragma unroll
            for (int ct = 0; ct < 4; ++ct)
                C[(size_t)node * 64 + ct * 16 + li] = f2bf(acc[ct][r] * dv);
        }
    }
}

// ===== GEMM+LN: Hb = (LN(relu(AG*dinv + b)) @ W) * dinv  (row-major in/out) =====
__global__ __launch_bounds__(256) void k_gemm_ln(const u16* __restrict__ AG,
                                                 const u16* __restrict__ Wtb,
                                                 const float* __restrict__ dinv,
                                                 const float* __restrict__ bias,
                                                 const float* __restrict__ g,
                                                 const float* __restrict__ beta,
                                                 u16* __restrict__ C, int N) {
    int tid = threadIdx.x;
    int wid = tid >> 6, l = tid & 63;
    int li = l & 15, hi = l >> 4;
    int n0 = blockIdx.x * 64 + wid * 16;
    if (n0 >= N) return;
    int k0 = hi * 8;

    s8v a[2];
    int nr = min(n0 + li, N - 1);
    ln_frags(AG, nr, hi, dinv, bias, g, beta, a);

    s8v b[4][2];
    #pragma unroll
    for (int ct = 0; ct < 4; ++ct)
        #pragma unroll
        for (int kk = 0; kk < 2; ++kk)
            b[ct][kk] = *reinterpret_cast<const s8v*>(Wtb + (ct * 16 + li) * 64 + kk * 32 + k0);

    f32x4 acc[4] = {{0.f, 0.f, 0.f, 0.f}, {0.f, 0.f, 0.f, 0.f},
                    {0.f, 0.f, 0.f, 0.f}, {0.f, 0.f, 0.f, 0.f}};
    #pragma unroll
    for (int kk = 0; kk < 2; ++kk)
        #pragma unroll
        for (int ct = 0; ct < 4; ++ct)
            acc[ct] = __builtin_amdgcn_mfma_f32_16x16x32_bf16(a[kk], b[ct][kk], acc[ct], 0, 0, 0);

    #pragma unroll
    for (int r = 0; r < 4; ++r) {
        int node = n0 + hi * 4 + r;
        if (node < N) {
            float dv = dinv[node];
            #pragma unroll
            for (int ct = 0; ct < 4; ++ct)
                C[(size_t)node * 64 + ct * 16 + li] = f2bf(acc[ct][r] * dv);
        }
    }
}

// ===== MLP head: out = relu(LN(relu(AG*dinv+b)) @ Wm1 + bm1) @ Wm2 + bm2 =====
__global__ __launch_bounds__(256) void k_mlp_ln(const u16* __restrict__ AG,
                                                const u16* __restrict__ Wtb,   // Wm1^T bf16
                                                const float* __restrict__ dinv,
                                                const float* __restrict__ bias,
                                                const float* __restrict__ g,
                                                const float* __restrict__ beta,
                                                const float* __restrict__ bm1,
                                                const float* __restrict__ Wm2,
                                                const float* __restrict__ bm2,
                                                float* __restrict__ out, int N) {
    int tid = threadIdx.x;
    int wid = tid >> 6, l = tid & 63;
    int li = l & 15, hi = l >> 4;
    int n0 = blockIdx.x * 64 + wid * 16;
    if (n0 >= N) return;
    int k0 = hi * 8;

    s8v a[2];
    int nr = min(n0 + li, N - 1);
    ln_frags(AG, nr, hi, dinv, bias, g, beta, a);

    s8v b[4][2];
    #pragma unroll
    for (int ct = 0; ct < 4; ++ct)
        #pragma unroll
        for (int kk = 0; kk < 2; ++kk)
            b[ct][kk] = *reinterpret_cast<const s8v*>(Wtb + (ct * 16 + li) * 64 + kk * 32 + k0);

    f32x4 acc[4] = {{0.f, 0.f, 0.f, 0.f}, {0.f, 0.f, 0.f, 0.f},
                    {0.f, 0.f, 0.f, 0.f}, {0.f, 0.f, 0.f, 0.f}};
    #pragma unroll
    for (int kk = 0; kk < 2; ++kk)
        #pragma unroll
        for (int ct = 0; ct < 4; ++ct)
            acc[ct] = __builtin_amdgcn_mfma_f32_16x16x32_bf16(a[kk], b[ct][kk], acc[ct], 0, 0, 0);

    float p[4][3];
    #pragma unroll
    for (int r = 0; r < 4; ++r)
        #pragma unroll
        for (int c = 0; c < 3; ++c) p[r][c] = 0.f;

    #pragma unroll
    for (int ct = 0; ct < 4; ++ct) {
        int col = ct * 16 + li;
        float bb = bm1[col];
        float w0 = Wm2[col * 3 + 0], w1 = Wm2[col * 3 + 1], w2 = Wm2[col * 3 + 2];
        #pragma unroll
        for (int r = 0; r < 4; ++r) {
            float v = fmaxf(acc[ct][r] + bb, 0.f);
            p[r][0] += v * w0;
            p[r][1] += v * w1;
            p[r][2] += v * w2;
        }
    }
    #pragma unroll
    for (int off = 1; off < 16; off <<= 1)
        #pragma unroll
        for (int r = 0; r < 4; ++r)
            #pragma unroll
            for (int c = 0; c < 3; ++c)
                p[r][c] += __shfl_xor(p[r][c], off);

    if (li == 0) {
        float o0 = bm2[0], o1 = bm2[1], o2 = bm2[2];
        #pragma unroll
        for (int r = 0; r < 4; ++r) {
            int node = n0 + hi * 4 + r;
            if (node < N) {
                out[(size_t)node * 3 + 0] = p[r][0] + o0;
                out[(size_t)node * 3 + 1] = p[r][1] + o1;
                out[(size_t)node * 3 + 2] = p[r][2] + o2;
            }
        }
    }
}

// ===== gather: 8 nodes/wave (degree-sorted), whole 128B rows, unroll x4 =====
// AG[d] = sum_nbr Hb[s] + Hb[d]   (Hb pre-scaled by dinv; edges partition-ordered)
__global__ __launch_bounds__(256) void k_gather(const u16* __restrict__ Hb,
                                                const int* __restrict__ row_ptr,
                                                const int* __restrict__ csr_src,
                                                const int* __restrict__ nodeperm,
                                                u16* __restrict__ AG, int N) {
    int tid = blockIdx.x * blockDim.x + threadIdx.x;
    int gid = tid >> 3;          // one 8-lane group per node
    if (gid >= N) return;
    int node = nodeperm[gid];    // degree-sorted -> uniform work within wave
    int fl = threadIdx.x & 7;    // feature octet
    const us8* H8 = reinterpret_cast<const us8*>(Hb);

    float a[8];
    #pragma unroll
    for (int k = 0; k < 8; ++k) a[k] = 0.f;

    int beg = row_ptr[node], end = row_ptr[node + 1];
    int j = beg;
    for (; j + 4 <= end; j += 4) {
        int s0 = csr_src[j];
        int s1 = csr_src[j + 1];
        int s2 = csr_src[j + 2];
        int s3 = csr_src[j + 3];
        us8 h0 = H8[(size_t)s0 * 8 + fl];
        us8 h1 = H8[(size_t)s1 * 8 + fl];
        us8 h2 = H8[(size_t)s2 * 8 + fl];
        us8 h3 = H8[(size_t)s3 * 8 + fl];
        #pragma unroll
        for (int k = 0; k < 8; ++k)
            a[k] += (bf2f(h0[k]) + bf2f(h1[k])) + (bf2f(h2[k]) + bf2f(h3[k]));
    }
    for (; j < end; ++j) {
        int s0 = csr_src[j];
        us8 h0 = H8[(size_t)s0 * 8 + fl];
        #pragma unroll
        for (int k = 0; k < 8; ++k)
            a[k] += bf2f(h0[k]);
    }
    {   // self loop (rows pre-scaled by dinv)
        us8 hs = H8[(size_t)node * 8 + fl];
        #pragma unroll
        for (int k = 0; k < 8; ++k)
            a[k] += bf2f(hs[k]);
    }
    us8 o;
    #pragma unroll
    for (int k = 0; k < 8; ++k) o[k] = f2bf(a[k]);
    *reinterpret_cast<us8*>(AG + (size_t)node * 64 + fl * 8) = o;
}

extern "C" void kernel_launch(void* const* d_in, const int* in_sizes, int n_in,
                              void* d_out, int out_size, void* d_ws, size_t ws_size,
                              hipStream_t stream) {
    const float* z     = (const float*)d_in[0];
    const int*   ei    = (const int*)d_in[1];
    const float* W1    = (const float*)d_in[2];
    const float* b1    = (const float*)d_in[3];
    const float* g1    = (const float*)d_in[4];
    const float* beta1 = (const float*)d_in[5];
    const float* W2    = (const float*)d_in[6];
    const float* b2    = (const float*)d_in[7];
    const float* g2    = (const float*)d_in[8];
    const float* beta2 = (const float*)d_in[9];
    const float* Wm1   = (const float*)d_in[10];
    const float* bm1   = (const float*)d_in[11];
    const float* Wm2   = (const float*)d_in[12];
    const float* bm2   = (const float*)d_in[13];

    int N = in_sizes[0] / 64;
    int E = in_sizes[1] / 2;
    const int* src = ei;
    const int* dst = ei + E;
    float* out = (float*)d_out;

    int NB  = (N + 255) >> 8;          // buckets (dst>>8)
    int NB1 = (E + EPB - 1) / EPB;     // edge blocks

    size_t N64 = (size_t)N * 64;
    auto rnd = [](size_t x) { return (x + 1023) & ~(size_t)1023; };
    int*   bbase     = (int*)d_ws;                       // NB+1
    int*   btot      = bbase + rnd(NB + 1);              // NB
    int*   dhist     = btot + rnd(NB);                   // 256 (degree bins)
    int*   deg       = dhist + 1024;                     // N
    int*   nodeperm  = deg + rnd(N);                     // N
    int*   blockhist = nodeperm + rnd(N);                // NB1*NB
    int*   entries   = blockhist + rnd((size_t)NB1 * NB);// E
    int*   row_ptr   = entries + rnd(E);                 // N+1
    float* dinv      = (float*)(row_ptr + rnd(N + 1));   // N
    int*   csr_src   = (int*)(dinv + rnd(N));            // E
    u16*   Hb        = (u16*)(csr_src + rnd(E));         // N*64 bf16, row-major, dinv-scaled
    u16*   AG        = Hb + rnd(N64);                    // N*64 bf16, raw gather sums
    u16*   Wtb       = AG + rnd(N64);                    // 3*64*64 bf16 transposed weights

    int nb_g = (N + 63) / 64;          // GEMM blocks (64 nodes, 4 waves x 16)
    int nb_gw = (N * 8 + 255) / 256;   // gather blocks (8 lanes per node)
    int nb_n = (N + 255) / 256;
    size_t lds_nb = (size_t)NB * sizeof(int);

    // ---- CSR build + weight prep + degree permutation ----
    k_p1_hist<<<NB1, 256, lds_nb, stream>>>(dst, blockhist, dhist, E, NB);
    k_p2a<<<NB, 512, 0, stream>>>(blockhist, btot, NB, NB1);
    k_p2b_prep<<<25, 512, 0, stream>>>(btot, bbase, row_ptr, NB, N, E, W1, W2, Wm1, Wtb);
    k_p3_scatter<<<NB1, 256, lds_nb, stream>>>(src, dst, blockhist, bbase, entries, E, NB);
    k_p4_csr<<<NB, 256, 0, stream>>>(entries, bbase, row_ptr, dinv, csr_src, deg, dhist, N);
    k_dscan<<<1, 256, 0, stream>>>(dhist);
    k_dperm<<<nb_n, 256, 0, stream>>>(deg, dhist, nodeperm, N);

    // ---- layer 1 ----
    k_gemm1<<<nb_g, 256, 0, stream>>>(z, Wtb, dinv, Hb, N);
    k_gather<<<nb_gw, 256, 0, stream>>>(Hb, row_ptr, csr_src, nodeperm, AG, N);
    // ---- layer 2 (LN1 fused into GEMM2 prologue) ----
    k_gemm_ln<<<nb_g, 256, 0, stream>>>(AG, Wtb + 4096, dinv, b1, g1, beta1, Hb, N);
    k_gather<<<nb_gw, 256, 0, stream>>>(Hb, row_ptr, csr_src, nodeperm, AG, N);
    // ---- MLP head (LN2 fused into prologue) ----
    k_mlp_ln<<<nb_g, 256, 0, stream>>>(AG, Wtb + 8192, dinv, b2, g2, beta2,
                                       bm1, Wm2, bm2, out, N);
}

// Round 13
// 170.398 us; speedup vs baseline: 4.0114x; 4.0114x over previous
//
#include <hip/hip_runtime.h>
#include <hip/hip_bf16.h>

#define LN_EPS 1e-5f
#define EPB 4096          // edges per block in bucket passes
typedef unsigned short u16;
typedef unsigned short us8 __attribute__((ext_vector_type(8)));
typedef short s8v __attribute__((ext_vector_type(8)));   // 8 bf16 (4 VGPRs) MFMA frag
typedef float f32x4 __attribute__((ext_vector_type(4))); // MFMA acc

static __device__ __forceinline__ float bf2f(u16 x) {
    return __uint_as_float(((unsigned int)x) << 16);
}
static __device__ __forceinline__ u16 f2bf(float f) {
    unsigned int u = __float_as_uint(f);
    return (u16)((u + 0x7fff + ((u >> 16) & 1)) >> 16);  // RNE
}

// ================= CSR build: two-level counting sort (bucket = dst>>8) =================
__global__ __launch_bounds__(256) void k_p1_hist(const int* __restrict__ dst,
                                                 int* __restrict__ blockhist,
                                                 int E, int NB) {
    extern __shared__ int h[];
    int b = blockIdx.x, t = threadIdx.x;
    for (int j = t; j < NB; j += 256) h[j] = 0;
    __syncthreads();
    int e0 = b * EPB, e1 = min(E, e0 + EPB);
    for (int e = e0 + t; e < e1; e += 256)
        atomicAdd(&h[dst[e] >> 8], 1);
    __syncthreads();
    for (int j = t; j < NB; j += 256)
        blockhist[(size_t)b * NB + j] = h[j];
}

__global__ __launch_bounds__(512) void k_p2a(int* __restrict__ blockhist,
                                             int* __restrict__ btot, int NB, int NB1) {
    __shared__ int sd[512];
    int k = blockIdx.x, t = threadIdx.x;
    int v = (t < NB1) ? blockhist[(size_t)t * NB + k] : 0;
    sd[t] = v;
    __syncthreads();
    for (int off = 1; off < 512; off <<= 1) {
        int x = (t >= off) ? sd[t - off] : 0;
        __syncthreads();
        sd[t] += x;
        __syncthreads();
    }
    if (t < NB1) blockhist[(size_t)t * NB + k] = sd[t] - v;
    if (t == 511) btot[k] = sd[511];
}

// block 0: exclusive-scan bucket totals -> bbase; blocks >=1: bf16-transpose weights
__global__ __launch_bounds__(512) void k_p2b_prep(const int* __restrict__ btot,
                                                  int* __restrict__ bbase,
                                                  int* __restrict__ row_ptr,
                                                  int NB, int N, int E,
                                                  const float* __restrict__ W1,
                                                  const float* __restrict__ W2,
                                                  const float* __restrict__ Wm1,
                                                  u16* __restrict__ Wtb) {
    if (blockIdx.x == 0) {
        __shared__ int sd[512];
        int t = threadIdx.x;
        int v = (t < NB) ? btot[t] : 0;
        sd[t] = v;
        __syncthreads();
        for (int off = 1; off < 512; off <<= 1) {
            int x = (t >= off) ? sd[t - off] : 0;
            __syncthreads();
            sd[t] += x;
            __syncthreads();
        }
        if (t < NB) bbase[t] = sd[t] - v;
        if (t == 0) { bbase[NB] = E; row_ptr[N] = E; }
    } else {
        int idx = (blockIdx.x - 1) * 512 + threadIdx.x;   // 3*4096 total
        if (idx < 3 * 4096) {
            int m = idx >> 12;
            int kc = idx & 4095;
            int col = kc >> 6, k = kc & 63;
            const float* W = (m == 0) ? W1 : (m == 1) ? W2 : Wm1;
            Wtb[idx] = f2bf(W[k * 64 + col]);
        }
    }
}

__global__ __launch_bounds__(256) void k_p3_scatter(const int* __restrict__ src,
                                                    const int* __restrict__ dst,
                                                    const int* __restrict__ blockhist,
                                                    const int* __restrict__ bbase,
                                                    int* __restrict__ entries,
                                                    int E, int NB) {
    extern __shared__ int cur[];
    int b = blockIdx.x, t = threadIdx.x;
    for (int j = t; j < NB; j += 256)
        cur[j] = bbase[j] + blockhist[(size_t)b * NB + j];
    __syncthreads();
    int e0 = b * EPB, e1 = min(E, e0 + EPB);
    for (int e = e0 + t; e < e1; e += 256) {
        int d = dst[e];
        int p = atomicAdd(&cur[d >> 8], 1);
        entries[p] = (src[e] << 8) | (d & 255);
    }
}

// p4: per-bucket counting sort by key (dst_local, src>>14) -> partition-ordered CSR
// plus in-LDS degree counting-sort of the bucket's 256 nodes -> nodeperm (NO global atomics)
__global__ __launch_bounds__(256) void k_p4_csr(const int* __restrict__ entries,
                                                const int* __restrict__ bbase,
                                                int* __restrict__ row_ptr,
                                                float* __restrict__ dinv,
                                                int* __restrict__ csr_src,
                                                int* __restrict__ nodeperm, int N) {
    __shared__ int bins[2048];
    __shared__ int sd[256];
    __shared__ int dh[256];
    int k = blockIdx.x, t = threadIdx.x;
    int b0 = bbase[k], b1 = bbase[k + 1];
    #pragma unroll
    for (int j = 0; j < 8; ++j) bins[t * 8 + j] = 0;
    dh[t] = 0;
    __syncthreads();
    for (int e = b0 + t; e < b1; e += 256) {
        int en = entries[e];
        int key = ((en & 255) << 3) | ((en >> 22) & 7);   // dst_local*8 + src_partition
        atomicAdd(&bins[key], 1);
    }
    __syncthreads();
    int c[8];
    int run = 0;
    #pragma unroll
    for (int j = 0; j < 8; ++j) {
        c[j] = run;
        run += bins[t * 8 + j];
    }
    sd[t] = run;
    __syncthreads();
    for (int off = 1; off < 256; off <<= 1) {
        int x = (t >= off) ? sd[t - off] : 0;
        __syncthreads();
        sd[t] += x;
        __syncthreads();
    }
    int excl = sd[t] - run;
    int node = (k << 8) + t;
    bool valid = node < N;
    int db = min(run, 255);
    if (valid) {
        row_ptr[node] = b0 + excl;
        dinv[node] = rsqrtf(1.0f + (float)run);
        atomicAdd(&dh[db], 1);          // LDS degree histogram
    }
    #pragma unroll
    for (int j = 0; j < 8; ++j) bins[t * 8 + j] = excl + c[j];
    __syncthreads();
    // exclusive scan of degree bins (reuse sd)
    int dv = dh[t];
    sd[t] = dv;
    __syncthreads();
    for (int off = 1; off < 256; off <<= 1) {
        int x = (t >= off) ? sd[t - off] : 0;
        __syncthreads();
        sd[t] += x;
        __syncthreads();
    }
    dh[t] = sd[t] - dv;                 // cursor base per degree bin
    __syncthreads();
    if (valid) {
        int r = atomicAdd(&dh[db], 1);  // rank within bucket, degree-sorted
        nodeperm[(k << 8) + r] = node;  // dense: full buckets fill 256, last fills N-k*256
    }
    __syncthreads();
    for (int e = b0 + t; e < b1; e += 256) {
        int en = entries[e];
        int key = ((en & 255) << 3) | ((en >> 22) & 7);
        int p = atomicAdd(&bins[key], 1);
        csr_src[b0 + p] = en >> 8;
    }
}

// ===== LN prologue (row-major AG): lane covers cols {hi*8..+7} u {32+hi*8..+7} of row nr;
//       stats across the 4 hi-lanes via shfl_xor(16,32); emits MFMA A-frags =====
static __device__ __forceinline__ void ln_frags(const u16* __restrict__ AG,
                                                int nr, int hi,
                                                const float* __restrict__ dinv,
                                                const float* __restrict__ bias,
                                                const float* __restrict__ g,
                                                const float* __restrict__ beta,
                                                s8v a[2]) {
    float dd = dinv[nr];
    int f0 = hi * 8;
    us8 lo = *reinterpret_cast<const us8*>(AG + (size_t)nr * 64 + f0);
    us8 hv = *reinterpret_cast<const us8*>(AG + (size_t)nr * 64 + 32 + f0);
    float v[16];
    #pragma unroll
    for (int j = 0; j < 8; ++j) {
        v[j] = fmaxf(bf2f(lo[j]) * dd + bias[f0 + j], 0.f);
        v[8 + j] = fmaxf(bf2f(hv[j]) * dd + bias[32 + f0 + j], 0.f);
    }
    float s = 0.f;
    #pragma unroll
    for (int j = 0; j < 16; ++j) s += v[j];
    s += __shfl_xor(s, 16); s += __shfl_xor(s, 32);
    float mu = s * (1.0f / 64.0f);
    float vs = 0.f;
    #pragma unroll
    for (int j = 0; j < 16; ++j) {
        float d = v[j] - mu;
        vs += d * d;
    }
    vs += __shfl_xor(vs, 16); vs += __shfl_xor(vs, 32);
    float r = rsqrtf(vs * (1.0f / 64.0f) + LN_EPS);
    #pragma unroll
    for (int j = 0; j < 8; ++j) {
        a[0][j] = (short)f2bf((v[j] - mu) * r * g[f0 + j] + beta[f0 + j]);
        a[1][j] = (short)f2bf((v[8 + j] - mu) * r * g[32 + f0 + j] + beta[32 + f0 + j]);
    }
}

// ===== GEMM1: Hb[n][64] = (z[n][:] @ W1) * dinv[n]  (fp32 A, bf16 out, row-major) =====
__global__ __launch_bounds__(256) void k_gemm1(const float* __restrict__ A,
                                               const u16* __restrict__ Wtb,
                                               const float* __restrict__ dinv,
                                               u16* __restrict__ C, int N) {
    int tid = threadIdx.x;
    int wid = tid >> 6, l = tid & 63;
    int li = l & 15, hi = l >> 4;
    int n0 = blockIdx.x * 64 + wid * 16;
    if (n0 >= N) return;
    int k0 = hi * 8;

    s8v a[2];
    int nr = min(n0 + li, N - 1);
    #pragma unroll
    for (int kk = 0; kk < 2; ++kk) {
        const float* p = A + (size_t)nr * 64 + kk * 32 + k0;
        float4 f0 = *reinterpret_cast<const float4*>(p);
        float4 f1 = *reinterpret_cast<const float4*>(p + 4);
        a[kk][0] = (short)f2bf(f0.x); a[kk][1] = (short)f2bf(f0.y);
        a[kk][2] = (short)f2bf(f0.z); a[kk][3] = (short)f2bf(f0.w);
        a[kk][4] = (short)f2bf(f1.x); a[kk][5] = (short)f2bf(f1.y);
        a[kk][6] = (short)f2bf(f1.z); a[kk][7] = (short)f2bf(f1.w);
    }

    s8v b[4][2];
    #pragma unroll
    for (int ct = 0; ct < 4; ++ct)
        #pragma unroll
        for (int kk = 0; kk < 2; ++kk)
            b[ct][kk] = *reinterpret_cast<const s8v*>(Wtb + (ct * 16 + li) * 64 + kk * 32 + k0);

    f32x4 acc[4] = {{0.f, 0.f, 0.f, 0.f}, {0.f, 0.f, 0.f, 0.f},
                    {0.f, 0.f, 0.f, 0.f}, {0.f, 0.f, 0.f, 0.f}};
    #pragma unroll
    for (int kk = 0; kk < 2; ++kk)
        #pragma unroll
        for (int ct = 0; ct < 4; ++ct)
            acc[ct] = __builtin_amdgcn_mfma_f32_16x16x32_bf16(a[kk], b[ct][kk], acc[ct], 0, 0, 0);

    #pragma unroll
    for (int r = 0; r < 4; ++r) {
        int node = n0 + hi * 4 + r;
        if (node < N) {
            float dv = dinv[node];
            #pragma unroll
            for (int ct = 0; ct < 4; ++ct)
                C[(size_t)node * 64 + ct * 16 + li] = f2bf(acc[ct][r] * dv);
        }
    }
}

// ===== GEMM+LN: Hb = (LN(relu(AG*dinv + b)) @ W) * dinv  (row-major in/out) =====
__global__ __launch_bounds__(256) void k_gemm_ln(const u16* __restrict__ AG,
                                                 const u16* __restrict__ Wtb,
                                                 const float* __restrict__ dinv,
                                                 const float* __restrict__ bias,
                                                 const float* __restrict__ g,
                                                 const float* __restrict__ beta,
                                                 u16* __restrict__ C, int N) {
    int tid = threadIdx.x;
    int wid = tid >> 6, l = tid & 63;
    int li = l & 15, hi = l >> 4;
    int n0 = blockIdx.x * 64 + wid * 16;
    if (n0 >= N) return;
    int k0 = hi * 8;

    s8v a[2];
    int nr = min(n0 + li, N - 1);
    ln_frags(AG, nr, hi, dinv, bias, g, beta, a);

    s8v b[4][2];
    #pragma unroll
    for (int ct = 0; ct < 4; ++ct)
        #pragma unroll
        for (int kk = 0; kk < 2; ++kk)
            b[ct][kk] = *reinterpret_cast<const s8v*>(Wtb + (ct * 16 + li) * 64 + kk * 32 + k0);

    f32x4 acc[4] = {{0.f, 0.f, 0.f, 0.f}, {0.f, 0.f, 0.f, 0.f},
                    {0.f, 0.f, 0.f, 0.f}, {0.f, 0.f, 0.f, 0.f}};
    #pragma unroll
    for (int kk = 0; kk < 2; ++kk)
        #pragma unroll
        for (int ct = 0; ct < 4; ++ct)
            acc[ct] = __builtin_amdgcn_mfma_f32_16x16x32_bf16(a[kk], b[ct][kk], acc[ct], 0, 0, 0);

    #pragma unroll
    for (int r = 0; r < 4; ++r) {
        int node = n0 + hi * 4 + r;
        if (node < N) {
            float dv = dinv[node];
            #pragma unroll
            for (int ct = 0; ct < 4; ++ct)
                C[(size_t)node * 64 + ct * 16 + li] = f2bf(acc[ct][r] * dv);
        }
    }
}

// ===== MLP head: out = relu(LN(relu(AG*dinv+b)) @ Wm1 + bm1) @ Wm2 + bm2 =====
__global__ __launch_bounds__(256) void k_mlp_ln(const u16* __restrict__ AG,
                                                const u16* __restrict__ Wtb,   // Wm1^T bf16
                                                const float* __restrict__ dinv,
                                                const float* __restrict__ bias,
                                                const float* __restrict__ g,
                                                const float* __restrict__ beta,
                                                const float* __restrict__ bm1,
                                                const float* __restrict__ Wm2,
                                                const float* __restrict__ bm2,
                                                float* __restrict__ out, int N) {
    int tid = threadIdx.x;
    int wid = tid >> 6, l = tid & 63;
    int li = l & 15, hi = l >> 4;
    int n0 = blockIdx.x * 64 + wid * 16;
    if (n0 >= N) return;
    int k0 = hi * 8;

    s8v a[2];
    int nr = min(n0 + li, N - 1);
    ln_frags(AG, nr, hi, dinv, bias, g, beta, a);

    s8v b[4][2];
    #pragma unroll
    for (int ct = 0; ct < 4; ++ct)
        #pragma unroll
        for (int kk = 0; kk < 2; ++kk)
            b[ct][kk] = *reinterpret_cast<const s8v*>(Wtb + (ct * 16 + li) * 64 + kk * 32 + k0);

    f32x4 acc[4] = {{0.f, 0.f, 0.f, 0.f}, {0.f, 0.f, 0.f, 0.f},
                    {0.f, 0.f, 0.f, 0.f}, {0.f, 0.f, 0.f, 0.f}};
    #pragma unroll
    for (int kk = 0; kk < 2; ++kk)
        #pragma unroll
        for (int ct = 0; ct < 4; ++ct)
            acc[ct] = __builtin_amdgcn_mfma_f32_16x16x32_bf16(a[kk], b[ct][kk], acc[ct], 0, 0, 0);

    float p[4][3];
    #pragma unroll
    for (int r = 0; r < 4; ++r)
        #pragma unroll
        for (int c = 0; c < 3; ++c) p[r][c] = 0.f;

    #pragma unroll
    for (int ct = 0; ct < 4; ++ct) {
        int col = ct * 16 + li;
        float bb = bm1[col];
        float w0 = Wm2[col * 3 + 0], w1 = Wm2[col * 3 + 1], w2 = Wm2[col * 3 + 2];
        #pragma unroll
        for (int r = 0; r < 4; ++r) {
            float v = fmaxf(acc[ct][r] + bb, 0.f);
            p[r][0] += v * w0;
            p[r][1] += v * w1;
            p[r][2] += v * w2;
        }
    }
    #pragma unroll
    for (int off = 1; off < 16; off <<= 1)
        #pragma unroll
        for (int r = 0; r < 4; ++r)
            #pragma unroll
            for (int c = 0; c < 3; ++c)
                p[r][c] += __shfl_xor(p[r][c], off);

    if (li == 0) {
        float o0 = bm2[0], o1 = bm2[1], o2 = bm2[2];
        #pragma unroll
        for (int r = 0; r < 4; ++r) {
            int node = n0 + hi * 4 + r;
            if (node < N) {
                out[(size_t)node * 3 + 0] = p[r][0] + o0;
                out[(size_t)node * 3 + 1] = p[r][1] + o1;
                out[(size_t)node * 3 + 2] = p[r][2] + o2;
            }
        }
    }
}

// ===== gather: 8 nodes/wave (bucket-local degree-sorted), whole 128B rows, unroll x4 =====
// AG[d] = sum_nbr Hb[s] + Hb[d]   (Hb pre-scaled by dinv; edges partition-ordered)
__global__ __launch_bounds__(256) void k_gather(const u16* __restrict__ Hb,
                                                const int* __restrict__ row_ptr,
                                                const int* __restrict__ csr_src,
                                                const int* __restrict__ nodeperm,
                                                u16* __restrict__ AG, int N) {
    int tid = blockIdx.x * blockDim.x + threadIdx.x;
    int gid = tid >> 3;          // one 8-lane group per node
    if (gid >= N) return;
    int node = nodeperm[gid];    // degree-sorted within bucket -> uniform wave work
    int fl = threadIdx.x & 7;    // feature octet
    const us8* H8 = reinterpret_cast<const us8*>(Hb);

    float a[8];
    #pragma unroll
    for (int k = 0; k < 8; ++k) a[k] = 0.f;

    int beg = row_ptr[node], end = row_ptr[node + 1];
    int j = beg;
    for (; j + 4 <= end; j += 4) {
        int s0 = csr_src[j];
        int s1 = csr_src[j + 1];
        int s2 = csr_src[j + 2];
        int s3 = csr_src[j + 3];
        us8 h0 = H8[(size_t)s0 * 8 + fl];
        us8 h1 = H8[(size_t)s1 * 8 + fl];
        us8 h2 = H8[(size_t)s2 * 8 + fl];
        us8 h3 = H8[(size_t)s3 * 8 + fl];
        #pragma unroll
        for (int k = 0; k < 8; ++k)
            a[k] += (bf2f(h0[k]) + bf2f(h1[k])) + (bf2f(h2[k]) + bf2f(h3[k]));
    }
    for (; j < end; ++j) {
        int s0 = csr_src[j];
        us8 h0 = H8[(size_t)s0 * 8 + fl];
        #pragma unroll
        for (int k = 0; k < 8; ++k)
            a[k] += bf2f(h0[k]);
    }
    {   // self loop (rows pre-scaled by dinv)
        us8 hs = H8[(size_t)node * 8 + fl];
        #pragma unroll
        for (int k = 0; k < 8; ++k)
            a[k] += bf2f(hs[k]);
    }
    us8 o;
    #pragma unroll
    for (int k = 0; k < 8; ++k) o[k] = f2bf(a[k]);
    *reinterpret_cast<us8*>(AG + (size_t)node * 64 + fl * 8) = o;
}

extern "C" void kernel_launch(void* const* d_in, const int* in_sizes, int n_in,
                              void* d_out, int out_size, void* d_ws, size_t ws_size,
                              hipStream_t stream) {
    const float* z     = (const float*)d_in[0];
    const int*   ei    = (const int*)d_in[1];
    const float* W1    = (const float*)d_in[2];
    const float* b1    = (const float*)d_in[3];
    const float* g1    = (const float*)d_in[4];
    const float* beta1 = (const float*)d_in[5];
    const float* W2    = (const float*)d_in[6];
    const float* b2    = (const float*)d_in[7];
    const float* g2    = (const float*)d_in[8];
    const float* beta2 = (const float*)d_in[9];
    const float* Wm1   = (const float*)d_in[10];
    const float* bm1   = (const float*)d_in[11];
    const float* Wm2   = (const float*)d_in[12];
    const float* bm2   = (const float*)d_in[13];

    int N = in_sizes[0] / 64;
    int E = in_sizes[1] / 2;
    const int* src = ei;
    const int* dst = ei + E;
    float* out = (float*)d_out;

    int NB  = (N + 255) >> 8;          // buckets (dst>>8)
    int NB1 = (E + EPB - 1) / EPB;     // edge blocks

    size_t N64 = (size_t)N * 64;
    auto rnd = [](size_t x) { return (x + 1023) & ~(size_t)1023; };
    int*   bbase     = (int*)d_ws;                       // NB+1
    int*   btot      = bbase + rnd(NB + 1);              // NB
    int*   nodeperm  = btot + rnd(NB);                   // N (bucket-local degree ranks)
    int*   blockhist = nodeperm + rnd(N);                // NB1*NB
    int*   entries   = blockhist + rnd((size_t)NB1 * NB);// E
    int*   row_ptr   = entries + rnd(E);                 // N+1
    float* dinv      = (float*)(row_ptr + rnd(N + 1));   // N
    int*   csr_src   = (int*)(dinv + rnd(N));            // E
    u16*   Hb        = (u16*)(csr_src + rnd(E));         // N*64 bf16, row-major, dinv-scaled
    u16*   AG        = Hb + rnd(N64);                    // N*64 bf16, raw gather sums
    u16*   Wtb       = AG + rnd(N64);                    // 3*64*64 bf16 transposed weights

    int nb_g = (N + 63) / 64;          // GEMM blocks (64 nodes, 4 waves x 16)
    int nb_gw = (N * 8 + 255) / 256;   // gather blocks (8 lanes per node)
    size_t lds_nb = (size_t)NB * sizeof(int);

    // ---- CSR build + weight prep (nodeperm built inside p4, LDS-only) ----
    k_p1_hist<<<NB1, 256, lds_nb, stream>>>(dst, blockhist, E, NB);
    k_p2a<<<NB, 512, 0, stream>>>(blockhist, btot, NB, NB1);
    k_p2b_prep<<<25, 512, 0, stream>>>(btot, bbase, row_ptr, NB, N, E, W1, W2, Wm1, Wtb);
    k_p3_scatter<<<NB1, 256, lds_nb, stream>>>(src, dst, blockhist, bbase, entries, E, NB);
    k_p4_csr<<<NB, 256, 0, stream>>>(entries, bbase, row_ptr, dinv, csr_src, nodeperm, N);

    // ---- layer 1 ----
    k_gemm1<<<nb_g, 256, 0, stream>>>(z, Wtb, dinv, Hb, N);
    k_gather<<<nb_gw, 256, 0, stream>>>(Hb, row_ptr, csr_src, nodeperm, AG, N);
    // ---- layer 2 (LN1 fused into GEMM2 prologue) ----
    k_gemm_ln<<<nb_g, 256, 0, stream>>>(AG, Wtb + 4096, dinv, b1, g1, beta1, Hb, N);
    k_gather<<<nb_gw, 256, 0, stream>>>(Hb, row_ptr, csr_src, nodeperm, AG, N);
    // ---- MLP head (LN2 fused into prologue) ----
    k_mlp_ln<<<nb_g, 256, 0, stream>>>(AG, Wtb + 8192, dinv, b2, g2, beta2,
                                       bm1, Wm2, bm2, out, N);
}

// Round 14
// 170.203 us; speedup vs baseline: 4.0160x; 1.0011x over previous
//
#include <hip/hip_runtime.h>
#include <hip/hip_bf16.h>

#define LN_EPS 1e-5f
#define EPB 4096          // edges per block in bucket passes
typedef unsigned short u16;
typedef unsigned short us8 __attribute__((ext_vector_type(8)));
typedef short s8v __attribute__((ext_vector_type(8)));   // 8 bf16 (4 VGPRs) MFMA frag
typedef float f32x4 __attribute__((ext_vector_type(4))); // MFMA acc

static __device__ __forceinline__ float bf2f(u16 x) {
    return __uint_as_float(((unsigned int)x) << 16);
}
static __device__ __forceinline__ u16 f2bf(float f) {
    unsigned int u = __float_as_uint(f);
    return (u16)((u + 0x7fff + ((u >> 16) & 1)) >> 16);  // RNE
}

// ================= CSR build: two-level counting sort (bucket = dst>>8) =================
__global__ __launch_bounds__(256) void k_p1_hist(const int* __restrict__ dst,
                                                 int* __restrict__ blockhist,
                                                 int E, int NB) {
    extern __shared__ int h[];
    int b = blockIdx.x, t = threadIdx.x;
    for (int j = t; j < NB; j += 256) h[j] = 0;
    __syncthreads();
    int e0 = b * EPB, e1 = min(E, e0 + EPB);
    for (int e = e0 + t; e < e1; e += 256)
        atomicAdd(&h[dst[e] >> 8], 1);
    __syncthreads();
    for (int j = t; j < NB; j += 256)
        blockhist[(size_t)b * NB + j] = h[j];
}

__global__ __launch_bounds__(512) void k_p2a(int* __restrict__ blockhist,
                                             int* __restrict__ btot, int NB, int NB1) {
    __shared__ int sd[512];
    int k = blockIdx.x, t = threadIdx.x;
    int v = (t < NB1) ? blockhist[(size_t)t * NB + k] : 0;
    sd[t] = v;
    __syncthreads();
    for (int off = 1; off < 512; off <<= 1) {
        int x = (t >= off) ? sd[t - off] : 0;
        __syncthreads();
        sd[t] += x;
        __syncthreads();
    }
    if (t < NB1) blockhist[(size_t)t * NB + k] = sd[t] - v;
    if (t == 511) btot[k] = sd[511];
}

// block 0: exclusive-scan bucket totals -> bbase; blocks >=1: bf16-transpose weights
__global__ __launch_bounds__(512) void k_p2b_prep(const int* __restrict__ btot,
                                                  int* __restrict__ bbase,
                                                  int* __restrict__ row_ptr,
                                                  int NB, int N, int E,
                                                  const float* __restrict__ W1,
                                                  const float* __restrict__ W2,
                                                  const float* __restrict__ Wm1,
                                                  u16* __restrict__ Wtb) {
    if (blockIdx.x == 0) {
        __shared__ int sd[512];
        int t = threadIdx.x;
        int v = (t < NB) ? btot[t] : 0;
        sd[t] = v;
        __syncthreads();
        for (int off = 1; off < 512; off <<= 1) {
            int x = (t >= off) ? sd[t - off] : 0;
            __syncthreads();
            sd[t] += x;
            __syncthreads();
        }
        if (t < NB) bbase[t] = sd[t] - v;
        if (t == 0) { bbase[NB] = E; row_ptr[N] = E; }
    } else {
        int idx = (blockIdx.x - 1) * 512 + threadIdx.x;   // 3*4096 total
        if (idx < 3 * 4096) {
            int m = idx >> 12;
            int kc = idx & 4095;
            int col = kc >> 6, k = kc & 63;
            const float* W = (m == 0) ? W1 : (m == 1) ? W2 : Wm1;
            Wtb[idx] = f2bf(W[k * 64 + col]);
        }
    }
}

__global__ __launch_bounds__(256) void k_p3_scatter(const int* __restrict__ src,
                                                    const int* __restrict__ dst,
                                                    const int* __restrict__ blockhist,
                                                    const int* __restrict__ bbase,
                                                    int* __restrict__ entries,
                                                    int E, int NB) {
    extern __shared__ int cur[];
    int b = blockIdx.x, t = threadIdx.x;
    for (int j = t; j < NB; j += 256)
        cur[j] = bbase[j] + blockhist[(size_t)b * NB + j];
    __syncthreads();
    int e0 = b * EPB, e1 = min(E, e0 + EPB);
    for (int e = e0 + t; e < e1; e += 256) {
        int d = dst[e];
        int p = atomicAdd(&cur[d >> 8], 1);
        entries[p] = (src[e] << 8) | (d & 255);
    }
}

// p4: per-bucket counting sort by key (dst_local, src>>14) -> partition-ordered CSR
// plus in-LDS degree counting-sort of the bucket's 256 nodes -> nodeperm (NO global atomics)
__global__ __launch_bounds__(256) void k_p4_csr(const int* __restrict__ entries,
                                                const int* __restrict__ bbase,
                                                int* __restrict__ row_ptr,
                                                float* __restrict__ dinv,
                                                int* __restrict__ csr_src,
                                                int* __restrict__ nodeperm, int N) {
    __shared__ int bins[2048];
    __shared__ int sd[256];
    __shared__ int dh[256];
    int k = blockIdx.x, t = threadIdx.x;
    int b0 = bbase[k], b1 = bbase[k + 1];
    #pragma unroll
    for (int j = 0; j < 8; ++j) bins[t * 8 + j] = 0;
    dh[t] = 0;
    __syncthreads();
    for (int e = b0 + t; e < b1; e += 256) {
        int en = entries[e];
        int key = ((en & 255) << 3) | ((en >> 22) & 7);   // dst_local*8 + src_partition
        atomicAdd(&bins[key], 1);
    }
    __syncthreads();
    int c[8];
    int run = 0;
    #pragma unroll
    for (int j = 0; j < 8; ++j) {
        c[j] = run;
        run += bins[t * 8 + j];
    }
    sd[t] = run;
    __syncthreads();
    for (int off = 1; off < 256; off <<= 1) {
        int x = (t >= off) ? sd[t - off] : 0;
        __syncthreads();
        sd[t] += x;
        __syncthreads();
    }
    int excl = sd[t] - run;
    int node = (k << 8) + t;
    bool valid = node < N;
    int db = min(run, 255);
    if (valid) {
        row_ptr[node] = b0 + excl;
        dinv[node] = rsqrtf(1.0f + (float)run);
        atomicAdd(&dh[db], 1);          // LDS degree histogram
    }
    #pragma unroll
    for (int j = 0; j < 8; ++j) bins[t * 8 + j] = excl + c[j];
    __syncthreads();
    // exclusive scan of degree bins (reuse sd)
    int dv = dh[t];
    sd[t] = dv;
    __syncthreads();
    for (int off = 1; off < 256; off <<= 1) {
        int x = (t >= off) ? sd[t - off] : 0;
        __syncthreads();
        sd[t] += x;
        __syncthreads();
    }
    dh[t] = sd[t] - dv;                 // cursor base per degree bin
    __syncthreads();
    if (valid) {
        int r = atomicAdd(&dh[db], 1);  // rank within bucket, degree-sorted
        nodeperm[(k << 8) + r] = node;  // dense: full buckets fill 256, last fills N-k*256
    }
    __syncthreads();
    for (int e = b0 + t; e < b1; e += 256) {
        int en = entries[e];
        int key = ((en & 255) << 3) | ((en >> 22) & 7);
        int p = atomicAdd(&bins[key], 1);
        csr_src[b0 + p] = en >> 8;
    }
}

// ===== LN prologue (row-major AG): lane covers cols {hi*8..+7} u {32+hi*8..+7} of row nr;
//       stats across the 4 hi-lanes via shfl_xor(16,32); emits MFMA A-frags =====
static __device__ __forceinline__ void ln_frags(const u16* __restrict__ AG,
                                                int nr, int hi,
                                                const float* __restrict__ dinv,
                                                const float* __restrict__ bias,
                                                const float* __restrict__ g,
                                                const float* __restrict__ beta,
                                                s8v a[2]) {
    float dd = dinv[nr];
    int f0 = hi * 8;
    us8 lo = *reinterpret_cast<const us8*>(AG + (size_t)nr * 64 + f0);
    us8 hv = *reinterpret_cast<const us8*>(AG + (size_t)nr * 64 + 32 + f0);
    float v[16];
    #pragma unroll
    for (int j = 0; j < 8; ++j) {
        v[j] = fmaxf(bf2f(lo[j]) * dd + bias[f0 + j], 0.f);
        v[8 + j] = fmaxf(bf2f(hv[j]) * dd + bias[32 + f0 + j], 0.f);
    }
    float s = 0.f;
    #pragma unroll
    for (int j = 0; j < 16; ++j) s += v[j];
    s += __shfl_xor(s, 16); s += __shfl_xor(s, 32);
    float mu = s * (1.0f / 64.0f);
    float vs = 0.f;
    #pragma unroll
    for (int j = 0; j < 16; ++j) {
        float d = v[j] - mu;
        vs += d * d;
    }
    vs += __shfl_xor(vs, 16); vs += __shfl_xor(vs, 32);
    float r = rsqrtf(vs * (1.0f / 64.0f) + LN_EPS);
    #pragma unroll
    for (int j = 0; j < 8; ++j) {
        a[0][j] = (short)f2bf((v[j] - mu) * r * g[f0 + j] + beta[f0 + j]);
        a[1][j] = (short)f2bf((v[8 + j] - mu) * r * g[32 + f0 + j] + beta[32 + f0 + j]);
    }
}

// ===== GEMM1: Hb[n][64] = (z[n][:] @ W1) * dinv[n]  (fp32 A, bf16 out, row-major) =====
__global__ __launch_bounds__(256) void k_gemm1(const float* __restrict__ A,
                                               const u16* __restrict__ Wtb,
                                               const float* __restrict__ dinv,
                                               u16* __restrict__ C, int N) {
    int tid = threadIdx.x;
    int wid = tid >> 6, l = tid & 63;
    int li = l & 15, hi = l >> 4;
    int n0 = blockIdx.x * 64 + wid * 16;
    if (n0 >= N) return;
    int k0 = hi * 8;

    s8v a[2];
    int nr = min(n0 + li, N - 1);
    #pragma unroll
    for (int kk = 0; kk < 2; ++kk) {
        const float* p = A + (size_t)nr * 64 + kk * 32 + k0;
        float4 f0 = *reinterpret_cast<const float4*>(p);
        float4 f1 = *reinterpret_cast<const float4*>(p + 4);
        a[kk][0] = (short)f2bf(f0.x); a[kk][1] = (short)f2bf(f0.y);
        a[kk][2] = (short)f2bf(f0.z); a[kk][3] = (short)f2bf(f0.w);
        a[kk][4] = (short)f2bf(f1.x); a[kk][5] = (short)f2bf(f1.y);
        a[kk][6] = (short)f2bf(f1.z); a[kk][7] = (short)f2bf(f1.w);
    }

    s8v b[4][2];
    #pragma unroll
    for (int ct = 0; ct < 4; ++ct)
        #pragma unroll
        for (int kk = 0; kk < 2; ++kk)
            b[ct][kk] = *reinterpret_cast<const s8v*>(Wtb + (ct * 16 + li) * 64 + kk * 32 + k0);

    f32x4 acc[4] = {{0.f, 0.f, 0.f, 0.f}, {0.f, 0.f, 0.f, 0.f},
                    {0.f, 0.f, 0.f, 0.f}, {0.f, 0.f, 0.f, 0.f}};
    #pragma unroll
    for (int kk = 0; kk < 2; ++kk)
        #pragma unroll
        for (int ct = 0; ct < 4; ++ct)
            acc[ct] = __builtin_amdgcn_mfma_f32_16x16x32_bf16(a[kk], b[ct][kk], acc[ct], 0, 0, 0);

    #pragma unroll
    for (int r = 0; r < 4; ++r) {
        int node = n0 + hi * 4 + r;
        if (node < N) {
            float dv = dinv[node];
            #pragma unroll
            for (int ct = 0; ct < 4; ++ct)
                C[(size_t)node * 64 + ct * 16 + li] = f2bf(acc[ct][r] * dv);
        }
    }
}

// ===== GEMM+LN: Hb = (LN(relu(AG*dinv + b)) @ W) * dinv  (row-major in/out) =====
__global__ __launch_bounds__(256) void k_gemm_ln(const u16* __restrict__ AG,
                                                 const u16* __restrict__ Wtb,
                                                 const float* __restrict__ dinv,
                                                 const float* __restrict__ bias,
                                                 const float* __restrict__ g,
                                                 const float* __restrict__ beta,
                                                 u16* __restrict__ C, int N) {
    int tid = threadIdx.x;
    int wid = tid >> 6, l = tid & 63;
    int li = l & 15, hi = l >> 4;
    int n0 = blockIdx.x * 64 + wid * 16;
    if (n0 >= N) return;
    int k0 = hi * 8;

    s8v a[2];
    int nr = min(n0 + li, N - 1);
    ln_frags(AG, nr, hi, dinv, bias, g, beta, a);

    s8v b[4][2];
    #pragma unroll
    for (int ct = 0; ct < 4; ++ct)
        #pragma unroll
        for (int kk = 0; kk < 2; ++kk)
            b[ct][kk] = *reinterpret_cast<const s8v*>(Wtb + (ct * 16 + li) * 64 + kk * 32 + k0);

    f32x4 acc[4] = {{0.f, 0.f, 0.f, 0.f}, {0.f, 0.f, 0.f, 0.f},
                    {0.f, 0.f, 0.f, 0.f}, {0.f, 0.f, 0.f, 0.f}};
    #pragma unroll
    for (int kk = 0; kk < 2; ++kk)
        #pragma unroll
        for (int ct = 0; ct < 4; ++ct)
            acc[ct] = __builtin_amdgcn_mfma_f32_16x16x32_bf16(a[kk], b[ct][kk], acc[ct], 0, 0, 0);

    #pragma unroll
    for (int r = 0; r < 4; ++r) {
        int node = n0 + hi * 4 + r;
        if (node < N) {
            float dv = dinv[node];
            #pragma unroll
            for (int ct = 0; ct < 4; ++ct)
                C[(size_t)node * 64 + ct * 16 + li] = f2bf(acc[ct][r] * dv);
        }
    }
}

// ===== MLP head: out = relu(LN(relu(AG*dinv+b)) @ Wm1 + bm1) @ Wm2 + bm2 =====
__global__ __launch_bounds__(256) void k_mlp_ln(const u16* __restrict__ AG,
                                                const u16* __restrict__ Wtb,   // Wm1^T bf16
                                                const float* __restrict__ dinv,
                                                const float* __restrict__ bias,
                                                const float* __restrict__ g,
                                                const float* __restrict__ beta,
                                                const float* __restrict__ bm1,
                                                const float* __restrict__ Wm2,
                                                const float* __restrict__ bm2,
                                                float* __restrict__ out, int N) {
    int tid = threadIdx.x;
    int wid = tid >> 6, l = tid & 63;
    int li = l & 15, hi = l >> 4;
    int n0 = blockIdx.x * 64 + wid * 16;
    if (n0 >= N) return;
    int k0 = hi * 8;

    s8v a[2];
    int nr = min(n0 + li, N - 1);
    ln_frags(AG, nr, hi, dinv, bias, g, beta, a);

    s8v b[4][2];
    #pragma unroll
    for (int ct = 0; ct < 4; ++ct)
        #pragma unroll
        for (int kk = 0; kk < 2; ++kk)
            b[ct][kk] = *reinterpret_cast<const s8v*>(Wtb + (ct * 16 + li) * 64 + kk * 32 + k0);

    f32x4 acc[4] = {{0.f, 0.f, 0.f, 0.f}, {0.f, 0.f, 0.f, 0.f},
                    {0.f, 0.f, 0.f, 0.f}, {0.f, 0.f, 0.f, 0.f}};
    #pragma unroll
    for (int kk = 0; kk < 2; ++kk)
        #pragma unroll
        for (int ct = 0; ct < 4; ++ct)
            acc[ct] = __builtin_amdgcn_mfma_f32_16x16x32_bf16(a[kk], b[ct][kk], acc[ct], 0, 0, 0);

    float p[4][3];
    #pragma unroll
    for (int r = 0; r < 4; ++r)
        #pragma unroll
        for (int c = 0; c < 3; ++c) p[r][c] = 0.f;

    #pragma unroll
    for (int ct = 0; ct < 4; ++ct) {
        int col = ct * 16 + li;
        float bb = bm1[col];
        float w0 = Wm2[col * 3 + 0], w1 = Wm2[col * 3 + 1], w2 = Wm2[col * 3 + 2];
        #pragma unroll
        for (int r = 0; r < 4; ++r) {
            float v = fmaxf(acc[ct][r] + bb, 0.f);
            p[r][0] += v * w0;
            p[r][1] += v * w1;
            p[r][2] += v * w2;
        }
    }
    #pragma unroll
    for (int off = 1; off < 16; off <<= 1)
        #pragma unroll
        for (int r = 0; r < 4; ++r)
            #pragma unroll
            for (int c = 0; c < 3; ++c)
                p[r][c] += __shfl_xor(p[r][c], off);

    if (li == 0) {
        float o0 = bm2[0], o1 = bm2[1], o2 = bm2[2];
        #pragma unroll
        for (int r = 0; r < 4; ++r) {
            int node = n0 + hi * 4 + r;
            if (node < N) {
                out[(size_t)node * 3 + 0] = p[r][0] + o0;
                out[(size_t)node * 3 + 1] = p[r][1] + o1;
                out[(size_t)node * 3 + 2] = p[r][2] + o2;
            }
        }
    }
}

// ===== gather: 8 nodes/wave (bucket-local degree-sorted), whole 128B rows, unroll x4 =====
// AG[d] = sum_nbr Hb[s] + Hb[d]   (Hb pre-scaled by dinv; edges partition-ordered)
__global__ __launch_bounds__(256) void k_gather(const u16* __restrict__ Hb,
                                                const int* __restrict__ row_ptr,
                                                const int* __restrict__ csr_src,
                                                const int* __restrict__ nodeperm,
                                                u16* __restrict__ AG, int N) {
    int tid = blockIdx.x * blockDim.x + threadIdx.x;
    int gid = tid >> 3;          // one 8-lane group per node
    if (gid >= N) return;
    int node = nodeperm[gid];    // degree-sorted within bucket -> uniform wave work
    int fl = threadIdx.x & 7;    // feature octet
    const us8* H8 = reinterpret_cast<const us8*>(Hb);

    float a[8];
    #pragma unroll
    for (int k = 0; k < 8; ++k) a[k] = 0.f;

    int beg = row_ptr[node], end = row_ptr[node + 1];
    int j = beg;
    for (; j + 4 <= end; j += 4) {
        int s0 = csr_src[j];
        int s1 = csr_src[j + 1];
        int s2 = csr_src[j + 2];
        int s3 = csr_src[j + 3];
        us8 h0 = H8[(size_t)s0 * 8 + fl];
        us8 h1 = H8[(size_t)s1 * 8 + fl];
        us8 h2 = H8[(size_t)s2 * 8 + fl];
        us8 h3 = H8[(size_t)s3 * 8 + fl];
        #pragma unroll
        for (int k = 0; k < 8; ++k)
            a[k] += (bf2f(h0[k]) + bf2f(h1[k])) + (bf2f(h2[k]) + bf2f(h3[k]));
    }
    for (; j < end; ++j) {
        int s0 = csr_src[j];
        us8 h0 = H8[(size_t)s0 * 8 + fl];
        #pragma unroll
        for (int k = 0; k < 8; ++k)
            a[k] += bf2f(h0[k]);
    }
    {   // self loop (rows pre-scaled by dinv)
        us8 hs = H8[(size_t)node * 8 + fl];
        #pragma unroll
        for (int k = 0; k < 8; ++k)
            a[k] += bf2f(hs[k]);
    }
    us8 o;
    #pragma unroll
    for (int k = 0; k < 8; ++k) o[k] = f2bf(a[k]);
    *reinterpret_cast<us8*>(AG + (size_t)node * 64 + fl * 8) = o;
}

extern "C" void kernel_launch(void* const* d_in, const int* in_sizes, int n_in,
                              void* d_out, int out_size, void* d_ws, size_t ws_size,
                              hipStream_t stream) {
    const float* z     = (const float*)d_in[0];
    const int*   ei    = (const int*)d_in[1];
    const float* W1    = (const float*)d_in[2];
    const float* b1    = (const float*)d_in[3];
    const float* g1    = (const float*)d_in[4];
    const float* beta1 = (const float*)d_in[5];
    const float* W2    = (const float*)d_in[6];
    const float* b2    = (const float*)d_in[7];
    const float* g2    = (const float*)d_in[8];
    const float* beta2 = (const float*)d_in[9];
    const float* Wm1   = (const float*)d_in[10];
    const float* bm1   = (const float*)d_in[11];
    const float* Wm2   = (const float*)d_in[12];
    const float* bm2   = (const float*)d_in[13];

    int N = in_sizes[0] / 64;
    int E = in_sizes[1] / 2;
    const int* src = ei;
    const int* dst = ei + E;
    float* out = (float*)d_out;

    int NB  = (N + 255) >> 8;          // buckets (dst>>8)
    int NB1 = (E + EPB - 1) / EPB;     // edge blocks

    size_t N64 = (size_t)N * 64;
    auto rnd = [](size_t x) { return (x + 1023) & ~(size_t)1023; };
    int*   bbase     = (int*)d_ws;                       // NB+1
    int*   btot      = bbase + rnd(NB + 1);              // NB
    int*   nodeperm  = btot + rnd(NB);                   // N (bucket-local degree ranks)
    int*   blockhist = nodeperm + rnd(N);                // NB1*NB
    int*   entries   = blockhist + rnd((size_t)NB1 * NB);// E
    int*   row_ptr   = entries + rnd(E);                 // N+1
    float* dinv      = (float*)(row_ptr + rnd(N + 1));   // N
    int*   csr_src   = (int*)(dinv + rnd(N));            // E
    u16*   Hb        = (u16*)(csr_src + rnd(E));         // N*64 bf16, row-major, dinv-scaled
    u16*   AG        = Hb + rnd(N64);                    // N*64 bf16, raw gather sums
    u16*   Wtb       = AG + rnd(N64);                    // 3*64*64 bf16 transposed weights

    int nb_g = (N + 63) / 64;          // GEMM blocks (64 nodes, 4 waves x 16)
    int nb_gw = (N * 8 + 255) / 256;   // gather blocks (8 lanes per node)
    size_t lds_nb = (size_t)NB * sizeof(int);

    // ---- CSR build + weight prep (nodeperm built inside p4, LDS-only) ----
    k_p1_hist<<<NB1, 256, lds_nb, stream>>>(dst, blockhist, E, NB);
    k_p2a<<<NB, 512, 0, stream>>>(blockhist, btot, NB, NB1);
    k_p2b_prep<<<25, 512, 0, stream>>>(btot, bbase, row_ptr, NB, N, E, W1, W2, Wm1, Wtb);
    k_p3_scatter<<<NB1, 256, lds_nb, stream>>>(src, dst, blockhist, bbase, entries, E, NB);
    k_p4_csr<<<NB, 256, 0, stream>>>(entries, bbase, row_ptr, dinv, csr_src, nodeperm, N);

    // ---- layer 1 ----
    k_gemm1<<<nb_g, 256, 0, stream>>>(z, Wtb, dinv, Hb, N);
    k_gather<<<nb_gw, 256, 0, stream>>>(Hb, row_ptr, csr_src, nodeperm, AG, N);
    // ---- layer 2 (LN1 fused into GEMM2 prologue) ----
    k_gemm_ln<<<nb_g, 256, 0, stream>>>(AG, Wtb + 4096, dinv, b1, g1, beta1, Hb, N);
    k_gather<<<nb_gw, 256, 0, stream>>>(Hb, row_ptr, csr_src, nodeperm, AG, N);
    // ---- MLP head (LN2 fused into prologue) ----
    k_mlp_ln<<<nb_g, 256, 0, stream>>>(AG, Wtb + 8192, dinv, b2, g2, beta2,
                                       bm1, Wm2, bm2, out, N);
}

// Round 15
// 155.572 us; speedup vs baseline: 4.3937x; 1.0940x over previous
//
#include <hip/hip_runtime.h>
#include <hip/hip_bf16.h>

#define LN_EPS 1e-5f
#define EPB 4096          // edges per block in bucket passes
typedef unsigned short u16;
typedef unsigned short us8 __attribute__((ext_vector_type(8)));
typedef short s8v __attribute__((ext_vector_type(8)));   // 8 bf16 (4 VGPRs) MFMA frag
typedef float f32x4 __attribute__((ext_vector_type(4))); // MFMA acc

static __device__ __forceinline__ float bf2f(u16 x) {
    return __uint_as_float(((unsigned int)x) << 16);
}
static __device__ __forceinline__ u16 f2bf(float f) {
    unsigned int u = __float_as_uint(f);
    return (u16)((u + 0x7fff + ((u >> 16) & 1)) >> 16);  // RNE
}

// ================= CSR build: two-level counting sort (bucket = dst>>8) =================
__global__ __launch_bounds__(256) void k_p1_hist(const int* __restrict__ dst,
                                                 int* __restrict__ blockhist,
                                                 int E, int NB) {
    extern __shared__ int h[];
    int b = blockIdx.x, t = threadIdx.x;
    for (int j = t; j < NB; j += 256) h[j] = 0;
    __syncthreads();
    int e0 = b * EPB, e1 = min(E, e0 + EPB);
    for (int e = e0 + t; e < e1; e += 256)
        atomicAdd(&h[dst[e] >> 8], 1);
    __syncthreads();
    for (int j = t; j < NB; j += 256)
        blockhist[(size_t)b * NB + j] = h[j];
}

__global__ __launch_bounds__(512) void k_p2a(int* __restrict__ blockhist,
                                             int* __restrict__ btot, int NB, int NB1) {
    __shared__ int sd[512];
    int k = blockIdx.x, t = threadIdx.x;
    int v = (t < NB1) ? blockhist[(size_t)t * NB + k] : 0;
    sd[t] = v;
    __syncthreads();
    for (int off = 1; off < 512; off <<= 1) {
        int x = (t >= off) ? sd[t - off] : 0;
        __syncthreads();
        sd[t] += x;
        __syncthreads();
    }
    if (t < NB1) blockhist[(size_t)t * NB + k] = sd[t] - v;
    if (t == 511) btot[k] = sd[511];
}

// block 0: exclusive-scan bucket totals -> bbase; blocks >=1: bf16-transpose weights
__global__ __launch_bounds__(512) void k_p2b_prep(const int* __restrict__ btot,
                                                  int* __restrict__ bbase,
                                                  int* __restrict__ row_ptr,
                                                  int NB, int N, int E,
                                                  const float* __restrict__ W1,
                                                  const float* __restrict__ W2,
                                                  const float* __restrict__ Wm1,
                                                  u16* __restrict__ Wtb) {
    if (blockIdx.x == 0) {
        __shared__ int sd[512];
        int t = threadIdx.x;
        int v = (t < NB) ? btot[t] : 0;
        sd[t] = v;
        __syncthreads();
        for (int off = 1; off < 512; off <<= 1) {
            int x = (t >= off) ? sd[t - off] : 0;
            __syncthreads();
            sd[t] += x;
            __syncthreads();
        }
        if (t < NB) bbase[t] = sd[t] - v;
        if (t == 0) { bbase[NB] = E; row_ptr[N] = E; }
    } else {
        int idx = (blockIdx.x - 1) * 512 + threadIdx.x;   // 3*4096 total
        if (idx < 3 * 4096) {
            int m = idx >> 12;
            int kc = idx & 4095;
            int col = kc >> 6, k = kc & 63;
            const float* W = (m == 0) ? W1 : (m == 1) ? W2 : Wm1;
            Wtb[idx] = f2bf(W[k * 64 + col]);
        }
    }
}

__global__ __launch_bounds__(256) void k_p3_scatter(const int* __restrict__ src,
                                                    const int* __restrict__ dst,
                                                    const int* __restrict__ blockhist,
                                                    const int* __restrict__ bbase,
                                                    int* __restrict__ entries,
                                                    int E, int NB) {
    extern __shared__ int cur[];
    int b = blockIdx.x, t = threadIdx.x;
    for (int j = t; j < NB; j += 256)
        cur[j] = bbase[j] + blockhist[(size_t)b * NB + j];
    __syncthreads();
    int e0 = b * EPB, e1 = min(E, e0 + EPB);
    for (int e = e0 + t; e < e1; e += 256) {
        int d = dst[e];
        int p = atomicAdd(&cur[d >> 8], 1);
        entries[p] = (src[e] << 8) | (d & 255);
    }
}

// p4: per-bucket counting sort by key (dst_local, src>>14) -> partition-ordered CSR
__global__ __launch_bounds__(256) void k_p4_csr(const int* __restrict__ entries,
                                                const int* __restrict__ bbase,
                                                int* __restrict__ row_ptr,
                                                float* __restrict__ dinv,
                                                int* __restrict__ csr_src, int N) {
    __shared__ int bins[2048];
    __shared__ int sd[256];
    int k = blockIdx.x, t = threadIdx.x;
    int b0 = bbase[k], b1 = bbase[k + 1];
    #pragma unroll
    for (int j = 0; j < 8; ++j) bins[t * 8 + j] = 0;
    __syncthreads();
    for (int e = b0 + t; e < b1; e += 256) {
        int en = entries[e];
        int key = ((en & 255) << 3) | ((en >> 22) & 7);   // dst_local*8 + src_partition
        atomicAdd(&bins[key], 1);
    }
    __syncthreads();
    int c[8];
    int run = 0;
    #pragma unroll
    for (int j = 0; j < 8; ++j) {
        c[j] = run;
        run += bins[t * 8 + j];
    }
    sd[t] = run;
    __syncthreads();
    for (int off = 1; off < 256; off <<= 1) {
        int x = (t >= off) ? sd[t - off] : 0;
        __syncthreads();
        sd[t] += x;
        __syncthreads();
    }
    int excl = sd[t] - run;
    int node = (k << 8) + t;
    if (node < N) {
        row_ptr[node] = b0 + excl;
        dinv[node] = rsqrtf(1.0f + (float)run);
    }
    #pragma unroll
    for (int j = 0; j < 8; ++j) bins[t * 8 + j] = excl + c[j];
    __syncthreads();
    for (int e = b0 + t; e < b1; e += 256) {
        int en = entries[e];
        int key = ((en & 255) << 3) | ((en >> 22) & 7);
        int p = atomicAdd(&bins[key], 1);
        csr_src[b0 + p] = en >> 8;
    }
}

// ===== LN prologue (row-major AG): lane covers cols {hi*8..+7} u {32+hi*8..+7} of row nr;
//       stats across the 4 hi-lanes via shfl_xor(16,32); emits MFMA A-frags =====
static __device__ __forceinline__ void ln_frags(const u16* __restrict__ AG,
                                                int nr, int hi,
                                                const float* __restrict__ dinv,
                                                const float* __restrict__ bias,
                                                const float* __restrict__ g,
                                                const float* __restrict__ beta,
                                                s8v a[2]) {
    float dd = dinv[nr];
    int f0 = hi * 8;
    us8 lo = *reinterpret_cast<const us8*>(AG + (size_t)nr * 64 + f0);
    us8 hv = *reinterpret_cast<const us8*>(AG + (size_t)nr * 64 + 32 + f0);
    float v[16];
    #pragma unroll
    for (int j = 0; j < 8; ++j) {
        v[j] = fmaxf(bf2f(lo[j]) * dd + bias[f0 + j], 0.f);
        v[8 + j] = fmaxf(bf2f(hv[j]) * dd + bias[32 + f0 + j], 0.f);
    }
    float s = 0.f;
    #pragma unroll
    for (int j = 0; j < 16; ++j) s += v[j];
    s += __shfl_xor(s, 16); s += __shfl_xor(s, 32);
    float mu = s * (1.0f / 64.0f);
    float vs = 0.f;
    #pragma unroll
    for (int j = 0; j < 16; ++j) {
        float d = v[j] - mu;
        vs += d * d;
    }
    vs += __shfl_xor(vs, 16); vs += __shfl_xor(vs, 32);
    float r = rsqrtf(vs * (1.0f / 64.0f) + LN_EPS);
    #pragma unroll
    for (int j = 0; j < 8; ++j) {
        a[0][j] = (short)f2bf((v[j] - mu) * r * g[f0 + j] + beta[f0 + j]);
        a[1][j] = (short)f2bf((v[8 + j] - mu) * r * g[32 + f0 + j] + beta[32 + f0 + j]);
    }
}

// ===== GEMM1: Hb[n][64] = (z[n][:] @ W1) * dinv[n]  (fp32 A, bf16 out, row-major) =====
__global__ __launch_bounds__(256) void k_gemm1(const float* __restrict__ A,
                                               const u16* __restrict__ Wtb,
                                               const float* __restrict__ dinv,
                                               u16* __restrict__ C, int N) {
    int tid = threadIdx.x;
    int wid = tid >> 6, l = tid & 63;
    int li = l & 15, hi = l >> 4;
    int n0 = blockIdx.x * 64 + wid * 16;
    if (n0 >= N) return;
    int k0 = hi * 8;

    s8v a[2];
    int nr = min(n0 + li, N - 1);
    #pragma unroll
    for (int kk = 0; kk < 2; ++kk) {
        const float* p = A + (size_t)nr * 64 + kk * 32 + k0;
        float4 f0 = *reinterpret_cast<const float4*>(p);
        float4 f1 = *reinterpret_cast<const float4*>(p + 4);
        a[kk][0] = (short)f2bf(f0.x); a[kk][1] = (short)f2bf(f0.y);
        a[kk][2] = (short)f2bf(f0.z); a[kk][3] = (short)f2bf(f0.w);
        a[kk][4] = (short)f2bf(f1.x); a[kk][5] = (short)f2bf(f1.y);
        a[kk][6] = (short)f2bf(f1.z); a[kk][7] = (short)f2bf(f1.w);
    }

    s8v b[4][2];
    #pragma unroll
    for (int ct = 0; ct < 4; ++ct)
        #pragma unroll
        for (int kk = 0; kk < 2; ++kk)
            b[ct][kk] = *reinterpret_cast<const s8v*>(Wtb + (ct * 16 + li) * 64 + kk * 32 + k0);

    f32x4 acc[4] = {{0.f, 0.f, 0.f, 0.f}, {0.f, 0.f, 0.f, 0.f},
                    {0.f, 0.f, 0.f, 0.f}, {0.f, 0.f, 0.f, 0.f}};
    #pragma unroll
    for (int kk = 0; kk < 2; ++kk)
        #pragma unroll
        for (int ct = 0; ct < 4; ++ct)
            acc[ct] = __builtin_amdgcn_mfma_f32_16x16x32_bf16(a[kk], b[ct][kk], acc[ct], 0, 0, 0);

    #pragma unroll
    for (int r = 0; r < 4; ++r) {
        int node = n0 + hi * 4 + r;
        if (node < N) {
            float dv = dinv[node];
            #pragma unroll
            for (int ct = 0; ct < 4; ++ct)
                C[(size_t)node * 64 + ct * 16 + li] = f2bf(acc[ct][r] * dv);
        }
    }
}

// ===== GEMM+LN: Hb = (LN(relu(AG*dinv + b)) @ W) * dinv  (row-major in/out) =====
__global__ __launch_bounds__(256) void k_gemm_ln(const u16* __restrict__ AG,
                                                 const u16* __restrict__ Wtb,
                                                 const float* __restrict__ dinv,
                                                 const float* __restrict__ bias,
                                                 const float* __restrict__ g,
                                                 const float* __restrict__ beta,
                                                 u16* __restrict__ C, int N) {
    int tid = threadIdx.x;
    int wid = tid >> 6, l = tid & 63;
    int li = l & 15, hi = l >> 4;
    int n0 = blockIdx.x * 64 + wid * 16;
    if (n0 >= N) return;
    int k0 = hi * 8;

    s8v a[2];
    int nr = min(n0 + li, N - 1);
    ln_frags(AG, nr, hi, dinv, bias, g, beta, a);

    s8v b[4][2];
    #pragma unroll
    for (int ct = 0; ct < 4; ++ct)
        #pragma unroll
        for (int kk = 0; kk < 2; ++kk)
            b[ct][kk] = *reinterpret_cast<const s8v*>(Wtb + (ct * 16 + li) * 64 + kk * 32 + k0);

    f32x4 acc[4] = {{0.f, 0.f, 0.f, 0.f}, {0.f, 0.f, 0.f, 0.f},
                    {0.f, 0.f, 0.f, 0.f}, {0.f, 0.f, 0.f, 0.f}};
    #pragma unroll
    for (int kk = 0; kk < 2; ++kk)
        #pragma unroll
        for (int ct = 0; ct < 4; ++ct)
            acc[ct] = __builtin_amdgcn_mfma_f32_16x16x32_bf16(a[kk], b[ct][kk], acc[ct], 0, 0, 0);

    #pragma unroll
    for (int r = 0; r < 4; ++r) {
        int node = n0 + hi * 4 + r;
        if (node < N) {
            float dv = dinv[node];
            #pragma unroll
            for (int ct = 0; ct < 4; ++ct)
                C[(size_t)node * 64 + ct * 16 + li] = f2bf(acc[ct][r] * dv);
        }
    }
}

// ===== MLP head: out = relu(LN(relu(AG*dinv+b)) @ Wm1 + bm1) @ Wm2 + bm2 =====
__global__ __launch_bounds__(256) void k_mlp_ln(const u16* __restrict__ AG,
                                                const u16* __restrict__ Wtb,   // Wm1^T bf16
                                                const float* __restrict__ dinv,
                                                const float* __restrict__ bias,
                                                const float* __restrict__ g,
                                                const float* __restrict__ beta,
                                                const float* __restrict__ bm1,
                                                const float* __restrict__ Wm2,
                                                const float* __restrict__ bm2,
                                                float* __restrict__ out, int N) {
    int tid = threadIdx.x;
    int wid = tid >> 6, l = tid & 63;
    int li = l & 15, hi = l >> 4;
    int n0 = blockIdx.x * 64 + wid * 16;
    if (n0 >= N) return;
    int k0 = hi * 8;

    s8v a[2];
    int nr = min(n0 + li, N - 1);
    ln_frags(AG, nr, hi, dinv, bias, g, beta, a);

    s8v b[4][2];
    #pragma unroll
    for (int ct = 0; ct < 4; ++ct)
        #pragma unroll
        for (int kk = 0; kk < 2; ++kk)
            b[ct][kk] = *reinterpret_cast<const s8v*>(Wtb + (ct * 16 + li) * 64 + kk * 32 + k0);

    f32x4 acc[4] = {{0.f, 0.f, 0.f, 0.f}, {0.f, 0.f, 0.f, 0.f},
                    {0.f, 0.f, 0.f, 0.f}, {0.f, 0.f, 0.f, 0.f}};
    #pragma unroll
    for (int kk = 0; kk < 2; ++kk)
        #pragma unroll
        for (int ct = 0; ct < 4; ++ct)
            acc[ct] = __builtin_amdgcn_mfma_f32_16x16x32_bf16(a[kk], b[ct][kk], acc[ct], 0, 0, 0);

    float p[4][3];
    #pragma unroll
    for (int r = 0; r < 4; ++r)
        #pragma unroll
        for (int c = 0; c < 3; ++c) p[r][c] = 0.f;

    #pragma unroll
    for (int ct = 0; ct < 4; ++ct) {
        int col = ct * 16 + li;
        float bb = bm1[col];
        float w0 = Wm2[col * 3 + 0], w1 = Wm2[col * 3 + 1], w2 = Wm2[col * 3 + 2];
        #pragma unroll
        for (int r = 0; r < 4; ++r) {
            float v = fmaxf(acc[ct][r] + bb, 0.f);
            p[r][0] += v * w0;
            p[r][1] += v * w1;
            p[r][2] += v * w2;
        }
    }
    #pragma unroll
    for (int off = 1; off < 16; off <<= 1)
        #pragma unroll
        for (int r = 0; r < 4; ++r)
            #pragma unroll
            for (int c = 0; c < 3; ++c)
                p[r][c] += __shfl_xor(p[r][c], off);

    if (li == 0) {
        float o0 = bm2[0], o1 = bm2[1], o2 = bm2[2];
        #pragma unroll
        for (int r = 0; r < 4; ++r) {
            int node = n0 + hi * 4 + r;
            if (node < N) {
                out[(size_t)node * 3 + 0] = p[r][0] + o0;
                out[(size_t)node * 3 + 1] = p[r][1] + o1;
                out[(size_t)node * 3 + 2] = p[r][2] + o2;
            }
        }
    }
}

// ===== gather: 8 nodes/wave (natural order), whole 128B rows, unroll x4 =====
// AG[d] = sum_nbr Hb[s] + Hb[d]   (Hb pre-scaled by dinv; edges partition-ordered)
__global__ __launch_bounds__(256) void k_gather(const u16* __restrict__ Hb,
                                                const int* __restrict__ row_ptr,
                                                const int* __restrict__ csr_src,
                                                u16* __restrict__ AG, int N) {
    int tid = blockIdx.x * blockDim.x + threadIdx.x;
    int node = tid >> 3;         // one 8-lane group per node
    if (node >= N) return;
    int fl = threadIdx.x & 7;    // feature octet
    const us8* H8 = reinterpret_cast<const us8*>(Hb);

    float a[8];
    #pragma unroll
    for (int k = 0; k < 8; ++k) a[k] = 0.f;

    int beg = row_ptr[node], end = row_ptr[node + 1];
    int j = beg;
    for (; j + 4 <= end; j += 4) {
        int s0 = csr_src[j];
        int s1 = csr_src[j + 1];
        int s2 = csr_src[j + 2];
        int s3 = csr_src[j + 3];
        us8 h0 = H8[(size_t)s0 * 8 + fl];
        us8 h1 = H8[(size_t)s1 * 8 + fl];
        us8 h2 = H8[(size_t)s2 * 8 + fl];
        us8 h3 = H8[(size_t)s3 * 8 + fl];
        #pragma unroll
        for (int k = 0; k < 8; ++k)
            a[k] += (bf2f(h0[k]) + bf2f(h1[k])) + (bf2f(h2[k]) + bf2f(h3[k]));
    }
    for (; j < end; ++j) {
        int s0 = csr_src[j];
        us8 h0 = H8[(size_t)s0 * 8 + fl];
        #pragma unroll
        for (int k = 0; k < 8; ++k)
            a[k] += bf2f(h0[k]);
    }
    {   // self loop (rows pre-scaled by dinv)
        us8 hs = H8[(size_t)node * 8 + fl];
        #pragma unroll
        for (int k = 0; k < 8; ++k)
            a[k] += bf2f(hs[k]);
    }
    us8 o;
    #pragma unroll
    for (int k = 0; k < 8; ++k) o[k] = f2bf(a[k]);
    *reinterpret_cast<us8*>(AG + (size_t)node * 64 + fl * 8) = o;
}

extern "C" void kernel_launch(void* const* d_in, const int* in_sizes, int n_in,
                              void* d_out, int out_size, void* d_ws, size_t ws_size,
                              hipStream_t stream) {
    const float* z     = (const float*)d_in[0];
    const int*   ei    = (const int*)d_in[1];
    const float* W1    = (const float*)d_in[2];
    const float* b1    = (const float*)d_in[3];
    const float* g1    = (const float*)d_in[4];
    const float* beta1 = (const float*)d_in[5];
    const float* W2    = (const float*)d_in[6];
    const float* b2    = (const float*)d_in[7];
    const float* g2    = (const float*)d_in[8];
    const float* beta2 = (const float*)d_in[9];
    const float* Wm1   = (const float*)d_in[10];
    const float* bm1   = (const float*)d_in[11];
    const float* Wm2   = (const float*)d_in[12];
    const float* bm2   = (const float*)d_in[13];

    int N = in_sizes[0] / 64;
    int E = in_sizes[1] / 2;
    const int* src = ei;
    const int* dst = ei + E;
    float* out = (float*)d_out;

    int NB  = (N + 255) >> 8;          // buckets (dst>>8)
    int NB1 = (E + EPB - 1) / EPB;     // edge blocks

    size_t N64 = (size_t)N * 64;
    auto rnd = [](size_t x) { return (x + 1023) & ~(size_t)1023; };
    int*   bbase     = (int*)d_ws;                       // NB+1
    int*   btot      = bbase + rnd(NB + 1);              // NB
    int*   blockhist = btot + rnd(NB);                   // NB1*NB
    int*   entries   = blockhist + rnd((size_t)NB1 * NB);// E
    int*   row_ptr   = entries + rnd(E);                 // N+1
    float* dinv      = (float*)(row_ptr + rnd(N + 1));   // N
    int*   csr_src   = (int*)(dinv + rnd(N));            // E
    u16*   Hb        = (u16*)(csr_src + rnd(E));         // N*64 bf16, row-major, dinv-scaled
    u16*   AG        = Hb + rnd(N64);                    // N*64 bf16, raw gather sums
    u16*   Wtb       = AG + rnd(N64);                    // 3*64*64 bf16 transposed weights

    int nb_g = (N + 63) / 64;          // GEMM blocks (64 nodes, 4 waves x 16)
    int nb_gw = (N * 8 + 255) / 256;   // gather blocks (8 lanes per node)
    size_t lds_nb = (size_t)NB * sizeof(int);

    // ---- CSR build + weight prep ----
    k_p1_hist<<<NB1, 256, lds_nb, stream>>>(dst, blockhist, E, NB);
    k_p2a<<<NB, 512, 0, stream>>>(blockhist, btot, NB, NB1);
    k_p2b_prep<<<25, 512, 0, stream>>>(btot, bbase, row_ptr, NB, N, E, W1, W2, Wm1, Wtb);
    k_p3_scatter<<<NB1, 256, lds_nb, stream>>>(src, dst, blockhist, bbase, entries, E, NB);
    k_p4_csr<<<NB, 256, 0, stream>>>(entries, bbase, row_ptr, dinv, csr_src, N);

    // ---- layer 1 ----
    k_gemm1<<<nb_g, 256, 0, stream>>>(z, Wtb, dinv, Hb, N);
    k_gather<<<nb_gw, 256, 0, stream>>>(Hb, row_ptr, csr_src, AG, N);
    // ---- layer 2 (LN1 fused into GEMM2 prologue) ----
    k_gemm_ln<<<nb_g, 256, 0, stream>>>(AG, Wtb + 4096, dinv, b1, g1, beta1, Hb, N);
    k_gather<<<nb_gw, 256, 0, stream>>>(Hb, row_ptr, csr_src, AG, N);
    // ---- MLP head (LN2 fused into prologue) ----
    k_mlp_ln<<<nb_g, 256, 0, stream>>>(AG, Wtb + 8192, dinv, b2, g2, beta2,
                                       bm1, Wm2, bm2, out, N);
}